// Round 1
// baseline (828.710 us; speedup 1.0000x reference)
//
#include <hip/hip_runtime.h>
#include <hip/hip_bf16.h>

// Problem: B=8, S=4096, H=8, HKV=2, D=64, HID=512. N_REP=4.
// Pipeline:
//   K1 gemm_qkv : x(32768x512 f32) @ [wq|wk|wv](512x768 f32) -> qkv bf16 (ws)
//   K2 attn     : per-position RoPE + 8x8 head-attention (GQA) -> out2 bf16 (ws, scrambled layout)
//   K3 gemm_out : out2(32768x512 bf16) @ wo(512x512 f32) -> d_out f32
//
// Scramble (reference transpose(0,2,1,3).reshape): attnout[b,t,h,d] ->
//   out2 row = h*512 + t/8, col = (t%8)*64 + d   (per batch).

#define M_TOT 32768
#define K_DIM 512
#define TS 64
#define KS 16

__global__ __launch_bounds__(256) void gemm_qkv(
    const float* __restrict__ x, const float* __restrict__ wq,
    const float* __restrict__ wk, const float* __restrict__ wv,
    __hip_bfloat16* __restrict__ qkv) {
  __shared__ float As[KS][TS + 1];
  __shared__ float Bs[KS][TS + 1];
  const int tid = threadIdx.x;
  const int m0 = blockIdx.x * TS;
  const int n0 = blockIdx.y * TS;  // [0,768)
  const float* W; int ldw, nc0;
  if (n0 < 512)      { W = wq; ldw = 512; nc0 = n0; }
  else if (n0 < 640) { W = wk; ldw = 128; nc0 = n0 - 512; }
  else               { W = wv; ldw = 128; nc0 = n0 - 640; }

  const int ty = tid >> 4, tx = tid & 15;
  float acc[4][4] = {};
  for (int k0 = 0; k0 < K_DIM; k0 += KS) {
    {
      int kk = tid & 15, mm = tid >> 4;
      #pragma unroll
      for (int i = 0; i < 4; ++i)
        As[kk][mm + 16 * i] = x[(size_t)(m0 + mm + 16 * i) * K_DIM + k0 + kk];
    }
    {
      int nn = tid & 63, kk = tid >> 6;
      #pragma unroll
      for (int i = 0; i < 4; ++i)
        Bs[kk + 4 * i][nn] = W[(size_t)(k0 + kk + 4 * i) * ldw + nc0 + nn];
    }
    __syncthreads();
    #pragma unroll
    for (int kk = 0; kk < KS; ++kk) {
      float a[4], b[4];
      #pragma unroll
      for (int i = 0; i < 4; ++i) a[i] = As[kk][ty * 4 + i];
      #pragma unroll
      for (int j = 0; j < 4; ++j) b[j] = Bs[kk][tx * 4 + j];
      #pragma unroll
      for (int i = 0; i < 4; ++i)
        #pragma unroll
        for (int j = 0; j < 4; ++j) acc[i][j] += a[i] * b[j];
    }
    __syncthreads();
  }
  #pragma unroll
  for (int i = 0; i < 4; ++i) {
    size_t m = m0 + ty * 4 + i;
    #pragma unroll
    for (int j = 0; j < 4; ++j)
      qkv[m * 768 + n0 + tx * 4 + j] = __float2bfloat16(acc[i][j]);
  }
}

__global__ __launch_bounds__(256) void gemm_out(
    const __hip_bfloat16* __restrict__ A, const float* __restrict__ W,
    float* __restrict__ C) {
  __shared__ float As[KS][TS + 1];
  __shared__ float Bs[KS][TS + 1];
  const int tid = threadIdx.x;
  const int m0 = blockIdx.x * TS;
  const int n0 = blockIdx.y * TS;
  const int ty = tid >> 4, tx = tid & 15;
  float acc[4][4] = {};
  for (int k0 = 0; k0 < K_DIM; k0 += KS) {
    {
      int kk = tid & 15, mm = tid >> 4;
      #pragma unroll
      for (int i = 0; i < 4; ++i)
        As[kk][mm + 16 * i] =
            __bfloat162float(A[(size_t)(m0 + mm + 16 * i) * K_DIM + k0 + kk]);
    }
    {
      int nn = tid & 63, kk = tid >> 6;
      #pragma unroll
      for (int i = 0; i < 4; ++i)
        Bs[kk + 4 * i][nn] = W[(size_t)(k0 + kk + 4 * i) * 512 + n0 + nn];
    }
    __syncthreads();
    #pragma unroll
    for (int kk = 0; kk < KS; ++kk) {
      float a[4], b[4];
      #pragma unroll
      for (int i = 0; i < 4; ++i) a[i] = As[kk][ty * 4 + i];
      #pragma unroll
      for (int j = 0; j < 4; ++j) b[j] = Bs[kk][tx * 4 + j];
      #pragma unroll
      for (int i = 0; i < 4; ++i)
        #pragma unroll
        for (int j = 0; j < 4; ++j) acc[i][j] += a[i] * b[j];
    }
    __syncthreads();
  }
  #pragma unroll
  for (int i = 0; i < 4; ++i) {
    size_t m = m0 + ty * 4 + i;
    #pragma unroll
    for (int j = 0; j < 4; ++j)
      C[m * 512 + n0 + tx * 4 + j] = acc[i][j];
  }
}

// One wave per (b,t) position.
__global__ __launch_bounds__(256) void attn_heads(
    const __hip_bfloat16* __restrict__ qkv, const float* __restrict__ fcos,
    const float* __restrict__ fsin, __hip_bfloat16* __restrict__ out2) {
  const int lane = threadIdx.x & 63;
  const int wid = blockIdx.x * (blockDim.x >> 6) + (threadIdx.x >> 6);
  const int b = wid >> 12;
  const int t = wid & 4095;
  const size_t row = (size_t)wid * 768;

  float q[8], k[2], v[2];
  #pragma unroll
  for (int h = 0; h < 8; ++h) q[h] = __bfloat162float(qkv[row + h * 64 + lane]);
  #pragma unroll
  for (int c = 0; c < 2; ++c) {
    k[c] = __bfloat162float(qkv[row + 512 + c * 64 + lane]);
    v[c] = __bfloat162float(qkv[row + 640 + c * 64 + lane]);
  }
  // RoPE (interleaved pairs): even lane holds xr, odd lane holds xi.
  const float cc = fcos[t * 32 + (lane >> 1)];
  const float ss = fsin[t * 32 + (lane >> 1)];
  const bool odd = lane & 1;
  #pragma unroll
  for (int h = 0; h < 8; ++h) {
    float other = __shfl_xor(q[h], 1);
    q[h] = odd ? (other * ss + q[h] * cc) : (q[h] * cc - other * ss);
  }
  #pragma unroll
  for (int c = 0; c < 2; ++c) {
    float other = __shfl_xor(k[c], 1);
    k[c] = odd ? (other * ss + k[c] * cc) : (k[c] * cc - other * ss);
  }
  // 16 distinct dots: q[h] . k[c], c = kv head (keys repeat 4x).
  float dot[8][2];
  #pragma unroll
  for (int h = 0; h < 8; ++h)
    #pragma unroll
    for (int c = 0; c < 2; ++c) {
      float p = q[h] * k[c];
      #pragma unroll
      for (int off = 32; off >= 1; off >>= 1) p += __shfl_xor(p, off);
      dot[h][c] = p * 0.125f;  // 1/sqrt(64)
    }
  // Analytic GQA softmax: keys 0..h; keys with same kv head have equal score.
  #pragma unroll
  for (int h = 0; h < 8; ++h) {
    int c0 = (h + 1 < 4) ? (h + 1) : 4;
    int c1 = (h + 1) - c0;
    float out;
    if (c1 > 0) {
      float s0 = dot[h][0], s1 = dot[h][1];
      float m = fmaxf(s0, s1);
      float e0 = expf(s0 - m), e1 = expf(s1 - m);
      float denom = (float)c0 * e0 + (float)c1 * e1;
      out = ((float)c0 * e0 * v[0] + (float)c1 * e1 * v[1]) / denom;
    } else {
      out = v[0];  // uniform softmax over identical scores
    }
    int tp = h * 512 + (t >> 3);
    int cp = (t & 7) * 64 + lane;
    out2[((size_t)(b * 4096 + tp)) * 512 + cp] = __float2bfloat16(out);
  }
}

extern "C" void kernel_launch(void* const* d_in, const int* in_sizes, int n_in,
                              void* d_out, int out_size, void* d_ws,
                              size_t ws_size, hipStream_t stream) {
  const float* x    = (const float*)d_in[0];
  const float* fcos = (const float*)d_in[1];
  const float* fsin = (const float*)d_in[2];
  const float* wq   = (const float*)d_in[3];
  const float* wk   = (const float*)d_in[4];
  const float* wv   = (const float*)d_in[5];
  const float* wo   = (const float*)d_in[6];
  float* out = (float*)d_out;

  __hip_bfloat16* qkv  = (__hip_bfloat16*)d_ws;
  __hip_bfloat16* out2 = (__hip_bfloat16*)((char*)d_ws + (size_t)M_TOT * 768 * 2);

  gemm_qkv<<<dim3(M_TOT / TS, 768 / TS), 256, 0, stream>>>(x, wq, wk, wv, qkv);
  attn_heads<<<dim3(M_TOT / 4), 256, 0, stream>>>(qkv, fcos, fsin, out2);
  gemm_out<<<dim3(M_TOT / TS, 512 / TS), 256, 0, stream>>>(out2, wo, out);
}

// Round 2
// 155.076 us; speedup vs baseline: 5.3439x; 5.3439x over previous
//
#include <hip/hip_runtime.h>
#include <hip/hip_bf16.h>

// B=8, S=4096, H=8, HKV=2, D=64, HID=512. M_TOT=32768, K=512.
// Pipeline:
//   K0 convert_x   : x f32 -> xb bf16                       (ws[0..32MB))
//   K1 transpose_w : [wq|wk|wv|wo] (KxN f32) -> wt bf16 NxK (ws[80MB..81.3MB))
//   K2 gemm<768>   : xb @ wt[0:768]  -> qkv bf16            (ws[32..80MB))
//   K3 attn_heads  : RoPE + analytic GQA 8x8 head-attn -> out2 bf16 (aliases xb)
//   K4 gemm<512>   : out2 @ wt[768:1280] -> d_out f32
// Scramble (ref transpose(0,2,1,3).reshape): attnout[b,t,h,d] ->
//   out2 row = h*512 + t/8, col = (t%8)*64 + d (per batch).

#define M_TOT 32768
#define K_DIM 512

typedef __bf16 bf16x8 __attribute__((ext_vector_type(8)));
typedef float f32x4 __attribute__((ext_vector_type(4)));
typedef unsigned short ushort8 __attribute__((ext_vector_type(8)));

__device__ __forceinline__ void gload_lds16(const __hip_bfloat16* g,
                                            __hip_bfloat16* l) {
  __builtin_amdgcn_global_load_lds(
      (const __attribute__((address_space(1))) unsigned int*)g,
      (__attribute__((address_space(3))) unsigned int*)l, 16, 0, 0);
}

__global__ __launch_bounds__(256) void convert_x(
    const float* __restrict__ x, __hip_bfloat16* __restrict__ xb) {
  size_t i = ((size_t)blockIdx.x * 256 + threadIdx.x) * 8;
  float4 a = *(const float4*)(x + i);
  float4 b = *(const float4*)(x + i + 4);
  ushort8 o;
  float va[8] = {a.x, a.y, a.z, a.w, b.x, b.y, b.z, b.w};
#pragma unroll
  for (int j = 0; j < 8; ++j) {
    __hip_bfloat16 t = __float2bfloat16(va[j]);
    o[j] = *(unsigned short*)&t;
  }
  *(ushort8*)(xb + i) = o;
}

// wt[n][k], n in [0,1280): n<512: wq col n; <640: wk col n-512; <768: wv col
// n-640; else wo col n-768.
__global__ __launch_bounds__(256) void transpose_w(
    const float* __restrict__ wq, const float* __restrict__ wk,
    const float* __restrict__ wv, const float* __restrict__ wo,
    __hip_bfloat16* __restrict__ wt) {
  __shared__ float tile[32][33];
  int n0 = blockIdx.x * 32, k0 = blockIdx.y * 32;
  const float* W;
  int ld, nc;
  if (n0 < 512)      { W = wq; ld = 512; nc = n0; }
  else if (n0 < 640) { W = wk; ld = 128; nc = n0 - 512; }
  else if (n0 < 768) { W = wv; ld = 128; nc = n0 - 640; }
  else               { W = wo; ld = 512; nc = n0 - 768; }
  int x = threadIdx.x & 31, y = threadIdx.x >> 5;
#pragma unroll
  for (int i = 0; i < 4; ++i)
    tile[y + 8 * i][x] = W[(size_t)(k0 + y + 8 * i) * ld + nc + x];
  __syncthreads();
#pragma unroll
  for (int i = 0; i < 4; ++i)
    wt[(size_t)(n0 + y + 8 * i) * 512 + k0 + x] =
        __float2bfloat16(tile[x][y + 8 * i]);
}

// MFMA GEMM: A (M_TOT x 512 bf16, row-major) @ Bt (N x 512 bf16, i.e. B^T)
// -> C (M_TOT x N). 128x128 tile, BK=32, 4 waves (2x2 of 64x64), dbuf LDS.
// LDS layout per buffer: [kb][row][8 bf16] (kb=k-block of 8), 16B per slot ->
// ds_read_b128 conflict-free, global_load_lds linear dest.
template <int N, typename OutT>
__global__ __launch_bounds__(256) void gemm_mfma(
    const __hip_bfloat16* __restrict__ A, const __hip_bfloat16* __restrict__ Bt,
    OutT* __restrict__ C) {
  __shared__ __hip_bfloat16 Al[2][4096];
  __shared__ __hip_bfloat16 Bl[2][4096];
  const int tid = threadIdx.x;
  const int lane = tid & 63;
  const int w = tid >> 6;
  const int wr = w >> 1, wc = w & 1;
  const int m0 = blockIdx.y * 128;
  const int n0 = blockIdx.x * 128;

  // staging: slot s (0..511) -> kb=s>>7, row=s&127; this thread covers
  // s0 = w*64+lane, s1 = 256+w*64+lane.
  const int s0 = w * 64 + lane;
  const int s1 = 256 + w * 64 + lane;
  const __hip_bfloat16* gA0 = A + (size_t)(m0 + (s0 & 127)) * 512 + (s0 >> 7) * 8;
  const __hip_bfloat16* gA1 = A + (size_t)(m0 + (s1 & 127)) * 512 + (s1 >> 7) * 8;
  const __hip_bfloat16* gB0 = Bt + (size_t)(n0 + (s0 & 127)) * 512 + (s0 >> 7) * 8;
  const __hip_bfloat16* gB1 = Bt + (size_t)(n0 + (s1 & 127)) * 512 + (s1 >> 7) * 8;

  f32x4 acc[4][4] = {};
  const int kb = lane >> 4;   // 0..3
  const int fr = lane & 15;

  // prologue: stage K-step 0 into buf 0
  {
    __hip_bfloat16* lA = &Al[0][(w * 64) * 8];
    __hip_bfloat16* lB = &Bl[0][(w * 64) * 8];
    gload_lds16(gA0, lA);
    gload_lds16(gA1, lA + 256 * 8);
    gload_lds16(gB0, lB);
    gload_lds16(gB1, lB + 256 * 8);
  }
  int cur = 0;
  for (int ks = 0; ks < 16; ++ks) {
    __syncthreads();  // drains vmcnt: buf[cur] ready; all waves done with buf[cur^1]
    if (ks < 15) {
      int ko = (ks + 1) * 32;
      __hip_bfloat16* lA = &Al[cur ^ 1][(w * 64) * 8];
      __hip_bfloat16* lB = &Bl[cur ^ 1][(w * 64) * 8];
      gload_lds16(gA0 + ko, lA);
      gload_lds16(gA1 + ko, lA + 256 * 8);
      gload_lds16(gB0 + ko, lB);
      gload_lds16(gB1 + ko, lB + 256 * 8);
    }
    bf16x8 af[4], bfr[4];
#pragma unroll
    for (int mi = 0; mi < 4; ++mi)
      af[mi] = *(const bf16x8*)&Al[cur][(kb * 128 + wr * 64 + mi * 16 + fr) * 8];
#pragma unroll
    for (int ni = 0; ni < 4; ++ni)
      bfr[ni] = *(const bf16x8*)&Bl[cur][(kb * 128 + wc * 64 + ni * 16 + fr) * 8];
#pragma unroll
    for (int mi = 0; mi < 4; ++mi)
#pragma unroll
      for (int ni = 0; ni < 4; ++ni)
        acc[mi][ni] = __builtin_amdgcn_mfma_f32_16x16x32_bf16(
            af[mi], bfr[ni], acc[mi][ni], 0, 0, 0);
    cur ^= 1;
  }
  // epilogue: C/D layout col=lane&15, row=(lane>>4)*4+reg  [m89]
#pragma unroll
  for (int mi = 0; mi < 4; ++mi) {
#pragma unroll
    for (int ni = 0; ni < 4; ++ni) {
      int col = n0 + wc * 64 + ni * 16 + (lane & 15);
#pragma unroll
      for (int r = 0; r < 4; ++r) {
        int row = m0 + wr * 64 + mi * 16 + (lane >> 4) * 4 + r;
        if constexpr (sizeof(OutT) == 2)
          C[(size_t)row * N + col] = __float2bfloat16(acc[mi][ni][r]);
        else
          C[(size_t)row * N + col] = acc[mi][ni][r];
      }
    }
  }
}

// One wave per (b,t) position: RoPE + analytic GQA softmax over 8 heads.
__global__ __launch_bounds__(256) void attn_heads(
    const __hip_bfloat16* __restrict__ qkv, const float* __restrict__ fcos,
    const float* __restrict__ fsin, __hip_bfloat16* __restrict__ out2) {
  const int lane = threadIdx.x & 63;
  const int wid = blockIdx.x * (blockDim.x >> 6) + (threadIdx.x >> 6);
  const int b = wid >> 12;
  const int t = wid & 4095;
  const size_t row = (size_t)wid * 768;

  float q[8], k[2], v[2];
#pragma unroll
  for (int h = 0; h < 8; ++h) q[h] = __bfloat162float(qkv[row + h * 64 + lane]);
#pragma unroll
  for (int c = 0; c < 2; ++c) {
    k[c] = __bfloat162float(qkv[row + 512 + c * 64 + lane]);
    v[c] = __bfloat162float(qkv[row + 640 + c * 64 + lane]);
  }
  const float cc = fcos[t * 32 + (lane >> 1)];
  const float ss = fsin[t * 32 + (lane >> 1)];
  const bool odd = lane & 1;
#pragma unroll
  for (int h = 0; h < 8; ++h) {
    float other = __shfl_xor(q[h], 1);
    q[h] = odd ? (other * ss + q[h] * cc) : (q[h] * cc - other * ss);
  }
#pragma unroll
  for (int c = 0; c < 2; ++c) {
    float other = __shfl_xor(k[c], 1);
    k[c] = odd ? (other * ss + k[c] * cc) : (k[c] * cc - other * ss);
  }
  float dot[8][2];
#pragma unroll
  for (int h = 0; h < 8; ++h)
#pragma unroll
    for (int c = 0; c < 2; ++c) {
      float p = q[h] * k[c];
#pragma unroll
      for (int off = 32; off >= 1; off >>= 1) p += __shfl_xor(p, off);
      dot[h][c] = p * 0.125f;
    }
#pragma unroll
  for (int h = 0; h < 8; ++h) {
    int c0 = (h + 1 < 4) ? (h + 1) : 4;
    int c1 = (h + 1) - c0;
    float out;
    if (c1 > 0) {
      float s0 = dot[h][0], s1 = dot[h][1];
      float m = fmaxf(s0, s1);
      float e0 = expf(s0 - m), e1 = expf(s1 - m);
      float denom = (float)c0 * e0 + (float)c1 * e1;
      out = ((float)c0 * e0 * v[0] + (float)c1 * e1 * v[1]) / denom;
    } else {
      out = v[0];
    }
    int tp = h * 512 + (t >> 3);
    int cp = (t & 7) * 64 + lane;
    out2[((size_t)(b * 4096 + tp)) * 512 + cp] = __float2bfloat16(out);
  }
}

extern "C" void kernel_launch(void* const* d_in, const int* in_sizes, int n_in,
                              void* d_out, int out_size, void* d_ws,
                              size_t ws_size, hipStream_t stream) {
  const float* x    = (const float*)d_in[0];
  const float* fcos = (const float*)d_in[1];
  const float* fsin = (const float*)d_in[2];
  const float* wq   = (const float*)d_in[3];
  const float* wk   = (const float*)d_in[4];
  const float* wv   = (const float*)d_in[5];
  const float* wo   = (const float*)d_in[6];
  float* out = (float*)d_out;

  __hip_bfloat16* xb   = (__hip_bfloat16*)d_ws;                       // 32MB
  __hip_bfloat16* out2 = xb;                                          // alias (xb dead after gemm_qkv)
  __hip_bfloat16* qkv  = (__hip_bfloat16*)((char*)d_ws + (size_t)M_TOT * 512 * 2);  // 48MB
  __hip_bfloat16* wt   = (__hip_bfloat16*)((char*)d_ws + (size_t)M_TOT * 512 * 2 +
                                           (size_t)M_TOT * 768 * 2);  // 1.25MB

  convert_x<<<dim3(M_TOT * 512 / 8 / 256), 256, 0, stream>>>(x, xb);
  transpose_w<<<dim3(1280 / 32, 512 / 32), 256, 0, stream>>>(wq, wk, wv, wo, wt);
  gemm_mfma<768, __hip_bfloat16><<<dim3(6, 256), 256, 0, stream>>>(xb, wt, qkv);
  attn_heads<<<dim3(M_TOT / 4), 256, 0, stream>>>(qkv, fcos, fsin, out2);
  gemm_mfma<512, float><<<dim3(4, 256), 256, 0, stream>>>(out2, wt + 768 * 512, out);
}

// Round 3
// 149.778 us; speedup vs baseline: 5.5329x; 1.0354x over previous
//
#include <hip/hip_runtime.h>
#include <hip/hip_bf16.h>

// B=8, S=4096, H=8, HKV=2, D=64, HID=512. M_TOT=32768, K=512.
// Pipeline:
//   K1 transpose_w : [wq|wk|wv|wo] (KxN f32) -> wt bf16 NxK   (ws[80MB..81.3MB))
//   K2 gemm_x_qkv  : x f32 (reg-cvt bf16) @ wt[0:768] -> qkv  (ws[0..48MB))
//   K3 attn_heads  : RoPE + analytic GQA 8x8 head-attn -> out2 (ws[48..80MB))
//   K4 gemm_mfma<4>: out2 @ wt[768:1280] -> d_out f32
// Both GEMMs use bijective XCD swizzle so all n-tiles of one m-panel run on
// the same XCD (A fetched once chip-wide instead of once per XCD).
// Scramble (ref transpose(0,2,1,3).reshape): attnout[b,t,h,d] ->
//   out2 row = h*512 + t/8, col = (t%8)*64 + d (per batch).

#define M_TOT 32768
#define K_DIM 512

typedef __bf16 bf16x8 __attribute__((ext_vector_type(8)));
typedef float f32x4 __attribute__((ext_vector_type(4)));

__device__ __forceinline__ void gload_lds16(const __hip_bfloat16* g,
                                            __hip_bfloat16* l) {
  __builtin_amdgcn_global_load_lds(
      (const __attribute__((address_space(1))) unsigned int*)g,
      (__attribute__((address_space(3))) unsigned int*)l, 16, 0, 0);
}

__device__ __forceinline__ bf16x8 cvt8(float4 a, float4 b) {
  bf16x8 r;
  r[0] = (__bf16)a.x; r[1] = (__bf16)a.y; r[2] = (__bf16)a.z; r[3] = (__bf16)a.w;
  r[4] = (__bf16)b.x; r[5] = (__bf16)b.y; r[6] = (__bf16)b.z; r[7] = (__bf16)b.w;
  return r;
}

// wt[n][k], n in [0,1280): n<512: wq col n; <640: wk col n-512; <768: wv col
// n-640; else wo col n-768.
__global__ __launch_bounds__(256) void transpose_w(
    const float* __restrict__ wq, const float* __restrict__ wk,
    const float* __restrict__ wv, const float* __restrict__ wo,
    __hip_bfloat16* __restrict__ wt) {
  __shared__ float tile[32][33];
  int n0 = blockIdx.x * 32, k0 = blockIdx.y * 32;
  const float* W;
  int ld, nc;
  if (n0 < 512)      { W = wq; ld = 512; nc = n0; }
  else if (n0 < 640) { W = wk; ld = 128; nc = n0 - 512; }
  else if (n0 < 768) { W = wv; ld = 128; nc = n0 - 640; }
  else               { W = wo; ld = 512; nc = n0 - 768; }
  int x = threadIdx.x & 31, y = threadIdx.x >> 5;
#pragma unroll
  for (int i = 0; i < 4; ++i)
    tile[y + 8 * i][x] = W[(size_t)(k0 + y + 8 * i) * ld + nc + x];
  __syncthreads();
#pragma unroll
  for (int i = 0; i < 4; ++i)
    wt[(size_t)(n0 + y + 8 * i) * 512 + k0 + x] =
        __float2bfloat16(tile[x][y + 8 * i]);
}

// Fused x-convert + QKV GEMM: x (32768x512 f32) @ wt[0:768] (768x512 bf16 B^T)
// -> qkv bf16. 128x128 tile, BK=32, 4 waves, dbuf LDS. A reg-staged with
// inline f32->bf16 cvt; B via global_load_lds. LDS: [kb][row][8bf16] slots.
__global__ __launch_bounds__(256) void gemm_x_qkv(
    const float* __restrict__ x, const __hip_bfloat16* __restrict__ wt,
    __hip_bfloat16* __restrict__ qkv) {
  __shared__ __hip_bfloat16 Al[2][4096];
  __shared__ __hip_bfloat16 Bl[2][4096];
  const int tid = threadIdx.x;
  const int lane = tid & 63;
  const int w = tid >> 6;
  const int wr = w >> 1, wc = w & 1;
  // XCD swizzle: nwg=1536, 192 per XCD, n-tile fastest within XCD.
  const int ng = (blockIdx.x & 7) * 192 + (blockIdx.x >> 3);
  const int m0 = (ng / 6) * 128, n0 = (ng % 6) * 128;

  const int r0 = tid & 127;         // slot row (slots tid and 256+tid share it)
  const int kb0 = tid >> 7;         // 0..1 (slot 256+tid -> kb0+2)
  const float* gA0 = x + (size_t)(m0 + r0) * 512 + kb0 * 8;
  const float* gA1 = gA0 + 16;
  const __hip_bfloat16* gB0 = wt + (size_t)(n0 + r0) * 512 + kb0 * 8;
  const __hip_bfloat16* gB1 = gB0 + 16;

  f32x4 acc[4][4] = {};
  const int kb = lane >> 4, fr = lane & 15;

  {  // prologue: stage ks=0 into buf 0
    float4 a0 = *(const float4*)gA0, a1 = *(const float4*)(gA0 + 4);
    float4 a2 = *(const float4*)gA1, a3 = *(const float4*)(gA1 + 4);
    gload_lds16(gB0, &Bl[0][(w * 64) * 8]);
    gload_lds16(gB1, &Bl[0][(256 + w * 64) * 8]);
    *(bf16x8*)&Al[0][tid * 8] = cvt8(a0, a1);
    *(bf16x8*)&Al[0][(256 + tid) * 8] = cvt8(a2, a3);
  }
  int cur = 0;
  for (int ks = 0; ks < 16; ++ks) {
    __syncthreads();  // buf[cur] ready (ds_writes + B vmcnt drained)
    float4 a0, a1, a2, a3;
    if (ks < 15) {
      const float* pA0 = gA0 + (ks + 1) * 32;
      const float* pA1 = gA1 + (ks + 1) * 32;
      a0 = *(const float4*)pA0; a1 = *(const float4*)(pA0 + 4);
      a2 = *(const float4*)pA1; a3 = *(const float4*)(pA1 + 4);
      int ko = (ks + 1) * 32;
      gload_lds16(gB0 + ko, &Bl[cur ^ 1][(w * 64) * 8]);
      gload_lds16(gB1 + ko, &Bl[cur ^ 1][(256 + w * 64) * 8]);
    }
    bf16x8 af[4], bfr[4];
#pragma unroll
    for (int mi = 0; mi < 4; ++mi)
      af[mi] = *(const bf16x8*)&Al[cur][(kb * 128 + wr * 64 + mi * 16 + fr) * 8];
#pragma unroll
    for (int ni = 0; ni < 4; ++ni)
      bfr[ni] = *(const bf16x8*)&Bl[cur][(kb * 128 + wc * 64 + ni * 16 + fr) * 8];
#pragma unroll
    for (int mi = 0; mi < 4; ++mi)
#pragma unroll
      for (int ni = 0; ni < 4; ++ni)
        acc[mi][ni] = __builtin_amdgcn_mfma_f32_16x16x32_bf16(
            af[mi], bfr[ni], acc[mi][ni], 0, 0, 0);
    if (ks < 15) {  // cvt + ds_write next A tile (vmcnt waited here, not before MFMA)
      *(bf16x8*)&Al[cur ^ 1][tid * 8] = cvt8(a0, a1);
      *(bf16x8*)&Al[cur ^ 1][(256 + tid) * 8] = cvt8(a2, a3);
    }
    cur ^= 1;
  }
#pragma unroll
  for (int mi = 0; mi < 4; ++mi) {
#pragma unroll
    for (int ni = 0; ni < 4; ++ni) {
      int col = n0 + wc * 64 + ni * 16 + (lane & 15);
#pragma unroll
      for (int r = 0; r < 4; ++r) {
        int row = m0 + wr * 64 + mi * 16 + (lane >> 4) * 4 + r;
        qkv[(size_t)row * 768 + col] = __float2bfloat16(acc[mi][ni][r]);
      }
    }
  }
}

// MFMA GEMM: A (M_TOT x 512 bf16) @ Bt (N x 512 bf16) -> C. NT = N/128.
template <int NT, typename OutT>
__global__ __launch_bounds__(256) void gemm_mfma(
    const __hip_bfloat16* __restrict__ A, const __hip_bfloat16* __restrict__ Bt,
    OutT* __restrict__ C) {
  constexpr int N = NT * 128;
  __shared__ __hip_bfloat16 Al[2][4096];
  __shared__ __hip_bfloat16 Bl[2][4096];
  const int tid = threadIdx.x;
  const int lane = tid & 63;
  const int w = tid >> 6;
  const int wr = w >> 1, wc = w & 1;
  constexpr int NWG = 256 * NT;
  const int ng = (blockIdx.x & 7) * (NWG / 8) + (blockIdx.x >> 3);
  const int m0 = (ng / NT) * 128;
  const int n0 = (ng % NT) * 128;

  const int s0 = tid;
  const int s1 = 256 + tid;
  const __hip_bfloat16* gA0 = A + (size_t)(m0 + (s0 & 127)) * 512 + (s0 >> 7) * 8;
  const __hip_bfloat16* gA1 = A + (size_t)(m0 + (s1 & 127)) * 512 + (s1 >> 7) * 8;
  const __hip_bfloat16* gB0 = Bt + (size_t)(n0 + (s0 & 127)) * 512 + (s0 >> 7) * 8;
  const __hip_bfloat16* gB1 = Bt + (size_t)(n0 + (s1 & 127)) * 512 + (s1 >> 7) * 8;

  f32x4 acc[4][4] = {};
  const int kb = lane >> 4;
  const int fr = lane & 15;

  {
    __hip_bfloat16* lA = &Al[0][(w * 64) * 8];
    __hip_bfloat16* lB = &Bl[0][(w * 64) * 8];
    gload_lds16(gA0, lA);
    gload_lds16(gA1, lA + 256 * 8);
    gload_lds16(gB0, lB);
    gload_lds16(gB1, lB + 256 * 8);
  }
  int cur = 0;
  for (int ks = 0; ks < 16; ++ks) {
    __syncthreads();
    if (ks < 15) {
      int ko = (ks + 1) * 32;
      __hip_bfloat16* lA = &Al[cur ^ 1][(w * 64) * 8];
      __hip_bfloat16* lB = &Bl[cur ^ 1][(w * 64) * 8];
      gload_lds16(gA0 + ko, lA);
      gload_lds16(gA1 + ko, lA + 256 * 8);
      gload_lds16(gB0 + ko, lB);
      gload_lds16(gB1 + ko, lB + 256 * 8);
    }
    bf16x8 af[4], bfr[4];
#pragma unroll
    for (int mi = 0; mi < 4; ++mi)
      af[mi] = *(const bf16x8*)&Al[cur][(kb * 128 + wr * 64 + mi * 16 + fr) * 8];
#pragma unroll
    for (int ni = 0; ni < 4; ++ni)
      bfr[ni] = *(const bf16x8*)&Bl[cur][(kb * 128 + wc * 64 + ni * 16 + fr) * 8];
#pragma unroll
    for (int mi = 0; mi < 4; ++mi)
#pragma unroll
      for (int ni = 0; ni < 4; ++ni)
        acc[mi][ni] = __builtin_amdgcn_mfma_f32_16x16x32_bf16(
            af[mi], bfr[ni], acc[mi][ni], 0, 0, 0);
    cur ^= 1;
  }
#pragma unroll
  for (int mi = 0; mi < 4; ++mi) {
#pragma unroll
    for (int ni = 0; ni < 4; ++ni) {
      int col = n0 + wc * 64 + ni * 16 + (lane & 15);
#pragma unroll
      for (int r = 0; r < 4; ++r) {
        int row = m0 + wr * 64 + mi * 16 + (lane >> 4) * 4 + r;
        if constexpr (sizeof(OutT) == 2)
          C[(size_t)row * N + col] = __float2bfloat16(acc[mi][ni][r]);
        else
          C[(size_t)row * N + col] = acc[mi][ni][r];
      }
    }
  }
}

// One wave per (b,t) position: RoPE + analytic GQA softmax over 8 heads.
__global__ __launch_bounds__(256) void attn_heads(
    const __hip_bfloat16* __restrict__ qkv, const float* __restrict__ fcos,
    const float* __restrict__ fsin, __hip_bfloat16* __restrict__ out2) {
  const int lane = threadIdx.x & 63;
  const int wid = blockIdx.x * (blockDim.x >> 6) + (threadIdx.x >> 6);
  const int b = wid >> 12;
  const int t = wid & 4095;
  const size_t row = (size_t)wid * 768;

  float q[8], k[2], v[2];
#pragma unroll
  for (int h = 0; h < 8; ++h) q[h] = __bfloat162float(qkv[row + h * 64 + lane]);
#pragma unroll
  for (int c = 0; c < 2; ++c) {
    k[c] = __bfloat162float(qkv[row + 512 + c * 64 + lane]);
    v[c] = __bfloat162float(qkv[row + 640 + c * 64 + lane]);
  }
  const float cc = fcos[t * 32 + (lane >> 1)];
  const float ss = fsin[t * 32 + (lane >> 1)];
  const bool odd = lane & 1;
#pragma unroll
  for (int h = 0; h < 8; ++h) {
    float other = __shfl_xor(q[h], 1);
    q[h] = odd ? (other * ss + q[h] * cc) : (q[h] * cc - other * ss);
  }
#pragma unroll
  for (int c = 0; c < 2; ++c) {
    float other = __shfl_xor(k[c], 1);
    k[c] = odd ? (other * ss + k[c] * cc) : (k[c] * cc - other * ss);
  }
  float dot[8][2];
#pragma unroll
  for (int h = 0; h < 8; ++h)
#pragma unroll
    for (int c = 0; c < 2; ++c) {
      float p = q[h] * k[c];
#pragma unroll
      for (int off = 32; off >= 1; off >>= 1) p += __shfl_xor(p, off);
      dot[h][c] = p * 0.125f;
    }
#pragma unroll
  for (int h = 0; h < 8; ++h) {
    int c0 = (h + 1 < 4) ? (h + 1) : 4;
    int c1 = (h + 1) - c0;
    float out;
    if (c1 > 0) {
      float s0 = dot[h][0], s1 = dot[h][1];
      float m = fmaxf(s0, s1);
      float e0 = expf(s0 - m), e1 = expf(s1 - m);
      float denom = (float)c0 * e0 + (float)c1 * e1;
      out = ((float)c0 * e0 * v[0] + (float)c1 * e1 * v[1]) / denom;
    } else {
      out = v[0];
    }
    int tp = h * 512 + (t >> 3);
    int cp = (t & 7) * 64 + lane;
    out2[((size_t)(b * 4096 + tp)) * 512 + cp] = __float2bfloat16(out);
  }
}

extern "C" void kernel_launch(void* const* d_in, const int* in_sizes, int n_in,
                              void* d_out, int out_size, void* d_ws,
                              size_t ws_size, hipStream_t stream) {
  const float* x    = (const float*)d_in[0];
  const float* fcos = (const float*)d_in[1];
  const float* fsin = (const float*)d_in[2];
  const float* wq   = (const float*)d_in[3];
  const float* wk   = (const float*)d_in[4];
  const float* wv   = (const float*)d_in[5];
  const float* wo   = (const float*)d_in[6];
  float* out = (float*)d_out;

  __hip_bfloat16* qkv  = (__hip_bfloat16*)d_ws;                                     // 48MB
  __hip_bfloat16* out2 = (__hip_bfloat16*)((char*)d_ws + (size_t)M_TOT * 768 * 2);  // 32MB
  __hip_bfloat16* wt   = (__hip_bfloat16*)((char*)d_ws + (size_t)M_TOT * 768 * 2 +
                                           (size_t)M_TOT * 512 * 2);                // 1.25MB

  transpose_w<<<dim3(1280 / 32, 512 / 32), 256, 0, stream>>>(wq, wk, wv, wo, wt);
  gemm_x_qkv<<<dim3(1536), 256, 0, stream>>>(x, wt, qkv);
  attn_heads<<<dim3(M_TOT / 4), 256, 0, stream>>>(qkv, fcos, fsin, out2);
  gemm_mfma<4, float><<<dim3(1024), 256, 0, stream>>>(out2, wt + 768 * 512, out);
}

// Round 4
// 140.044 us; speedup vs baseline: 5.9175x; 1.0695x over previous
//
#include <hip/hip_runtime.h>
#include <hip/hip_bf16.h>

// B=8, S=4096, H=8, HKV=2, D=64, HID=512. M_TOT=32768, K=512.
// Pipeline:
//   K0 convert_x   : x f32 -> xb bf16                         (ws[0..32MB))
//   K1 transpose_w : [wq|wk|wv|wo] (KxN f32) -> wt bf16 NxK   (ws[80..81.3MB))
//   K2 gemm2<6>    : xb @ wt[0:768]  -> qkv bf16              (ws[32..80MB))
//   K3 attn_heads  : RoPE + analytic GQA 8x8 head-attn -> out2 (aliases xb)
//   K4 gemm2<4>    : out2 @ wt[768:1280] -> d_out f32
// GEMM: 256x128 tile, BK=32, 8 waves (4x2 of 64x64), dbuf LDS (48KB),
// global_load_lds width-16, bijective XCD swizzle (n-tile fastest per XCD).
// Scramble (ref transpose(0,2,1,3).reshape): attnout[b,t,h,d] ->
//   out2 row = h*512 + t/8, col = (t%8)*64 + d (per batch).

#define M_TOT 32768
#define K_DIM 512

typedef __bf16 bf16x8 __attribute__((ext_vector_type(8)));
typedef float f32x4 __attribute__((ext_vector_type(4)));
typedef unsigned short ushort8 __attribute__((ext_vector_type(8)));

__device__ __forceinline__ void gload_lds16(const __hip_bfloat16* g,
                                            __hip_bfloat16* l) {
  __builtin_amdgcn_global_load_lds(
      (const __attribute__((address_space(1))) unsigned int*)g,
      (__attribute__((address_space(3))) unsigned int*)l, 16, 0, 0);
}

__global__ __launch_bounds__(256) void convert_x(
    const float* __restrict__ x, __hip_bfloat16* __restrict__ xb) {
  size_t i = ((size_t)blockIdx.x * 256 + threadIdx.x) * 8;
  float4 a = *(const float4*)(x + i);
  float4 b = *(const float4*)(x + i + 4);
  ushort8 o;
  float va[8] = {a.x, a.y, a.z, a.w, b.x, b.y, b.z, b.w};
#pragma unroll
  for (int j = 0; j < 8; ++j) {
    __hip_bfloat16 t = __float2bfloat16(va[j]);
    o[j] = *(unsigned short*)&t;
  }
  *(ushort8*)(xb + i) = o;
}

// wt[n][k], n in [0,1280): n<512: wq col n; <640: wk col n-512; <768: wv col
// n-640; else wo col n-768.
__global__ __launch_bounds__(256) void transpose_w(
    const float* __restrict__ wq, const float* __restrict__ wk,
    const float* __restrict__ wv, const float* __restrict__ wo,
    __hip_bfloat16* __restrict__ wt) {
  __shared__ float tile[32][33];
  int n0 = blockIdx.x * 32, k0 = blockIdx.y * 32;
  const float* W;
  int ld, nc;
  if (n0 < 512)      { W = wq; ld = 512; nc = n0; }
  else if (n0 < 640) { W = wk; ld = 128; nc = n0 - 512; }
  else if (n0 < 768) { W = wv; ld = 128; nc = n0 - 640; }
  else               { W = wo; ld = 512; nc = n0 - 768; }
  int x = threadIdx.x & 31, y = threadIdx.x >> 5;
#pragma unroll
  for (int i = 0; i < 4; ++i)
    tile[y + 8 * i][x] = W[(size_t)(k0 + y + 8 * i) * ld + nc + x];
  __syncthreads();
#pragma unroll
  for (int i = 0; i < 4; ++i)
    wt[(size_t)(n0 + y + 8 * i) * 512 + k0 + x] =
        __float2bfloat16(tile[x][y + 8 * i]);
}

// MFMA GEMM: A (M_TOT x 512 bf16 row-major) @ Bt (N x 512 bf16, B^T) -> C.
// 256x128 tile, 8 waves as 4x2 of 64x64 sub-tiles. NT = N/128.
// LDS per buffer: A [kb 0..3][row 0..255][8bf16], B [kb 0..3][row 0..127][8bf16].
template <int NT, typename OutT>
__global__ __launch_bounds__(512) void gemm_mfma2(
    const __hip_bfloat16* __restrict__ A, const __hip_bfloat16* __restrict__ Bt,
    OutT* __restrict__ C) {
  constexpr int N = NT * 128;
  __shared__ __hip_bfloat16 Al[2][8192];
  __shared__ __hip_bfloat16 Bl[2][4096];
  const int tid = threadIdx.x;
  const int lane = tid & 63;
  const int w = tid >> 6;            // 0..7
  const int wr = w >> 1, wc = w & 1; // 4x2
  constexpr int NWG = 128 * NT;      // (M_TOT/256) * NT
  const int ng = (blockIdx.x & 7) * (NWG / 8) + (blockIdx.x >> 3);
  const int m0 = (ng / NT) * 256;
  const int n0 = (ng % NT) * 128;

  // A slots: s=tid -> (row=tid&255, kb=tid>>8 in {0,1}); s=512+tid -> kb+2.
  // B slot : s=tid -> (row=tid&127, kb=tid>>7 in 0..3).
  const __hip_bfloat16* gA0 =
      A + (size_t)(m0 + (tid & 255)) * 512 + (tid >> 8) * 8;
  const __hip_bfloat16* gA1 = gA0 + 16;  // kb+2
  const __hip_bfloat16* gB0 =
      Bt + (size_t)(n0 + (tid & 127)) * 512 + (tid >> 7) * 8;

  f32x4 acc[4][4] = {};
  const int kb = lane >> 4, fr = lane & 15;

  {  // prologue: stage ks=0 into buf 0 (LDS dest linear in tid, 16B/slot)
    gload_lds16(gA0, &Al[0][(w * 64) * 8]);
    gload_lds16(gA1, &Al[0][(512 + w * 64) * 8]);
    gload_lds16(gB0, &Bl[0][(w * 64) * 8]);
  }
  int cur = 0;
  for (int ks = 0; ks < 16; ++ks) {
    __syncthreads();  // buf[cur] ready (each wave drained its vmcnt)
    if (ks < 15) {
      int ko = (ks + 1) * 32;
      gload_lds16(gA0 + ko, &Al[cur ^ 1][(w * 64) * 8]);
      gload_lds16(gA1 + ko, &Al[cur ^ 1][(512 + w * 64) * 8]);
      gload_lds16(gB0 + ko, &Bl[cur ^ 1][(w * 64) * 8]);
    }
    bf16x8 af[4], bfr[4];
#pragma unroll
    for (int mi = 0; mi < 4; ++mi)
      af[mi] =
          *(const bf16x8*)&Al[cur][(kb * 256 + wr * 64 + mi * 16 + fr) * 8];
#pragma unroll
    for (int ni = 0; ni < 4; ++ni)
      bfr[ni] =
          *(const bf16x8*)&Bl[cur][(kb * 128 + wc * 64 + ni * 16 + fr) * 8];
#pragma unroll
    for (int mi = 0; mi < 4; ++mi)
#pragma unroll
      for (int ni = 0; ni < 4; ++ni)
        acc[mi][ni] = __builtin_amdgcn_mfma_f32_16x16x32_bf16(
            af[mi], bfr[ni], acc[mi][ni], 0, 0, 0);
    cur ^= 1;
  }
  // C/D layout: col=lane&15, row=(lane>>4)*4+reg  [m89]
#pragma unroll
  for (int mi = 0; mi < 4; ++mi) {
#pragma unroll
    for (int ni = 0; ni < 4; ++ni) {
      int col = n0 + wc * 64 + ni * 16 + (lane & 15);
#pragma unroll
      for (int r = 0; r < 4; ++r) {
        int row = m0 + wr * 64 + mi * 16 + (lane >> 4) * 4 + r;
        if constexpr (sizeof(OutT) == 2)
          C[(size_t)row * N + col] = __float2bfloat16(acc[mi][ni][r]);
        else
          C[(size_t)row * N + col] = acc[mi][ni][r];
      }
    }
  }
}

// One wave per (b,t) position: RoPE + analytic GQA softmax over 8 heads.
__global__ __launch_bounds__(256) void attn_heads(
    const __hip_bfloat16* __restrict__ qkv, const float* __restrict__ fcos,
    const float* __restrict__ fsin, __hip_bfloat16* __restrict__ out2) {
  const int lane = threadIdx.x & 63;
  const int wid = blockIdx.x * (blockDim.x >> 6) + (threadIdx.x >> 6);
  const int b = wid >> 12;
  const int t = wid & 4095;
  const size_t row = (size_t)wid * 768;

  float q[8], k[2], v[2];
#pragma unroll
  for (int h = 0; h < 8; ++h) q[h] = __bfloat162float(qkv[row + h * 64 + lane]);
#pragma unroll
  for (int c = 0; c < 2; ++c) {
    k[c] = __bfloat162float(qkv[row + 512 + c * 64 + lane]);
    v[c] = __bfloat162float(qkv[row + 640 + c * 64 + lane]);
  }
  const float cc = fcos[t * 32 + (lane >> 1)];
  const float ss = fsin[t * 32 + (lane >> 1)];
  const bool odd = lane & 1;
#pragma unroll
  for (int h = 0; h < 8; ++h) {
    float other = __shfl_xor(q[h], 1);
    q[h] = odd ? (other * ss + q[h] * cc) : (q[h] * cc - other * ss);
  }
#pragma unroll
  for (int c = 0; c < 2; ++c) {
    float other = __shfl_xor(k[c], 1);
    k[c] = odd ? (other * ss + k[c] * cc) : (k[c] * cc - other * ss);
  }
  float dot[8][2];
#pragma unroll
  for (int h = 0; h < 8; ++h)
#pragma unroll
    for (int c = 0; c < 2; ++c) {
      float p = q[h] * k[c];
#pragma unroll
      for (int off = 32; off >= 1; off >>= 1) p += __shfl_xor(p, off);
      dot[h][c] = p * 0.125f;
    }
#pragma unroll
  for (int h = 0; h < 8; ++h) {
    int c0 = (h + 1 < 4) ? (h + 1) : 4;
    int c1 = (h + 1) - c0;
    float out;
    if (c1 > 0) {
      float s0 = dot[h][0], s1 = dot[h][1];
      float m = fmaxf(s0, s1);
      float e0 = expf(s0 - m), e1 = expf(s1 - m);
      float denom = (float)c0 * e0 + (float)c1 * e1;
      out = ((float)c0 * e0 * v[0] + (float)c1 * e1 * v[1]) / denom;
    } else {
      out = v[0];
    }
    int tp = h * 512 + (t >> 3);
    int cp = (t & 7) * 64 + lane;
    out2[((size_t)(b * 4096 + tp)) * 512 + cp] = __float2bfloat16(out);
  }
}

extern "C" void kernel_launch(void* const* d_in, const int* in_sizes, int n_in,
                              void* d_out, int out_size, void* d_ws,
                              size_t ws_size, hipStream_t stream) {
  const float* x    = (const float*)d_in[0];
  const float* fcos = (const float*)d_in[1];
  const float* fsin = (const float*)d_in[2];
  const float* wq   = (const float*)d_in[3];
  const float* wk   = (const float*)d_in[4];
  const float* wv   = (const float*)d_in[5];
  const float* wo   = (const float*)d_in[6];
  float* out = (float*)d_out;

  __hip_bfloat16* xb   = (__hip_bfloat16*)d_ws;  // 32MB
  __hip_bfloat16* out2 = xb;                      // alias (xb dead after gemm qkv)
  __hip_bfloat16* qkv  = (__hip_bfloat16*)((char*)d_ws + (size_t)M_TOT * 512 * 2);  // 48MB
  __hip_bfloat16* wt   = (__hip_bfloat16*)((char*)d_ws + (size_t)M_TOT * 512 * 2 +
                                           (size_t)M_TOT * 768 * 2);  // 1.25MB

  convert_x<<<dim3(M_TOT * 512 / 8 / 256), 256, 0, stream>>>(x, xb);
  transpose_w<<<dim3(1280 / 32, 512 / 32), 256, 0, stream>>>(wq, wk, wv, wo, wt);
  gemm_mfma2<6, __hip_bfloat16><<<dim3(768), 512, 0, stream>>>(xb, wt, qkv);
  attn_heads<<<dim3(M_TOT / 4), 256, 0, stream>>>(qkv, fcos, fsin, out2);
  gemm_mfma2<4, float><<<dim3(512), 512, 0, stream>>>(out2, wt + 768 * 512, out);
}